// Round 14
// baseline (170.034 us; speedup 1.0000x reference)
//
#include <hip/hip_runtime.h>

typedef unsigned char uchar;
typedef unsigned long long ull;
typedef __attribute__((ext_vector_type(2))) unsigned long long ullx2;
typedef __attribute__((ext_vector_type(4))) float floatx4;
typedef __attribute__((ext_vector_type(4))) unsigned int uintx4;

#define NB_IMG 18496      // 136 y * 2 p * 68 xh pixel slots per batch image
#define WHALF 9216        // bytes per eval per weight half (9*4*32*8)
#define AREG 16352        // A-tile LDS bytes (max 680 px * 24 B + 32 guard)

// ---- fp32 -> fp8 e4m3 (OCP), RNE ----
__device__ __forceinline__ uchar f2e4(float x) {
    float a = fabsf(x);
    unsigned s = (__float_as_uint(x) >> 24) & 0x80u;
    if (a >= 448.f) return (uchar)(s | 0x7E);
    if (a < 0.015625f) {
        int m = (int)rintf(a * 512.f);
        return (uchar)(s | (unsigned)m);
    }
    unsigned u = __float_as_uint(a);
    unsigned r = u + 0x7FFFFu + ((u >> 20) & 1u);
    unsigned e8 = (r >> 23) - 120u;
    return (uchar)(s | (e8 << 3) | ((r >> 20) & 7u));
}

// 16-lane DPP row sum (all lanes get row total)
__device__ __forceinline__ float row16sum(float v) {
    v += __int_as_float(__builtin_amdgcn_update_dpp(0, __float_as_int(v), 0x128, 0xf, 0xf, false));
    v += __int_as_float(__builtin_amdgcn_update_dpp(0, __float_as_int(v), 0x124, 0xf, 0xf, false));
    v += __int_as_float(__builtin_amdgcn_update_dpp(0, __float_as_int(v), 0x122, 0xf, 0xf, false));
    v += __int_as_float(__builtin_amdgcn_update_dpp(0, __float_as_int(v), 0x121, 0xf, 0xf, false));
    return v;
}

__device__ __forceinline__ void eval_geom(int e, int& sy0, int& sx0, int& cch, int& s_idx) {
    if (e < 3) { sy0 = 0; sx0 = 0; cch = e; s_idx = -1; }
    else {
        int u = e - 3; int s = (u % 9) / 3; cch = u % 3; s_idx = s;
        sy0 = (s == 1) ? 0 : 1;
        sx0 = (s == 2) ? 0 : 1;
    }
}

__device__ __forceinline__ bool tap_active(int e, int ci, int dy, int dx,
                                           int sy0, int sx0, int cch, int s_idx) {
    if (ci >= 3) return true;
    int py = (sy0 + dy - 1) & 1;
    int px = (sx0 + dx - 1) & 1;
    if (e < 3) return (py == 0 && px == 0) && (ci < cch);
    if (py == 0 && px == 0) return true;
    int sp = (py == 1 && px == 1) ? 0 : ((py == 0 && px == 1) ? 1 : 2);
    return (sp < s_idx) || (sp == s_idx && ci < cch);
}

// ---- merged prepass: cvt (blocks 0..2311) + weight pack (blocks 2312..2500) ----
__global__ __launch_bounds__(256) void prep_kernel(
    const float* __restrict__ value, const float* __restrict__ dp,
    const float* __restrict__ W1,
    uchar* __restrict__ imgbf, uchar* __restrict__ wbfA, uchar* __restrict__ wbfB,
    float* __restrict__ out)
{
    const int bid = blockIdx.x;
    if (bid < 2312) {
        const int t = bid * 256 + threadIdx.x;   // 591872 slots exactly
        const int b = t / NB_IMG;
        const int r = t - b * NB_IMG;
        const int y = r / 136;
        const int rr = r - y * 136;
        const int p = rr / 68;
        const int xh = rr - p * 68;
        const int yi = y - 4;
        const int xi = 2 * (xh - 2) + p;
        unsigned d[8];
        #pragma unroll
        for (int i = 0; i < 8; ++i) d[i] = 0;
        if ((unsigned)yi < 128u && (unsigned)xi < 128u) {
            const int o = yi * 128 + xi;
            const float* vb = value + (size_t)b * 3 * 16384 + o;
            const float* pb = dp + (size_t)b * 16 * 16384 + o;
            #pragma unroll
            for (int i = 0; i < 3; ++i) d[i >> 2] |= (unsigned)f2e4(vb[i * 16384]) << ((i & 3) * 8);
            #pragma unroll
            for (int i = 0; i < 16; ++i) {
                const int ci = 3 + i;
                d[ci >> 2] |= (unsigned)f2e4(pb[i * 16384]) << ((ci & 3) * 8);
            }
        }
        uchar* dst = imgbf + (size_t)t * 32;
        uintx4 v0, v1;
        v0[0] = d[0]; v0[1] = d[1]; v0[2] = d[2]; v0[3] = d[3];
        v1[0] = d[4]; v1[1] = d[5]; v1[2] = d[6]; v1[3] = d[7];
        *(uintx4*)dst = v0;
        *(uintx4*)(dst + 16) = v1;
    } else {
        // masked fp8 weights, fragment-major; cols 0..31 -> wbfA, 32..63 -> wbfB
        const int q = bid - 2312;                // 0..188
        const int e = q / 9, tap = q % 9;
        const int g = threadIdx.x >> 6, n = threadIdx.x & 63;
        int sy0, sx0, cch, s_idx;
        eval_geom(e, sy0, sx0, cch, s_idx);
        const int dy = tap / 3, dx = tap % 3;
        const float* wrow = W1 + ((size_t)e * 64 + n) * 171;
        ull v = 0;
        #pragma unroll
        for (int qq = 0; qq < 8; ++qq) {
            const int ci = g * 8 + qq;
            float w = 0.f;
            if (ci < 19 && tap_active(e, ci, dy, dx, sy0, sx0, cch, s_idx))
                w = wrow[ci * 9 + tap];
            v |= (ull)f2e4(w) << (qq * 8);
        }
        if (n < 32) *(ull*)&wbfA[(size_t)e * WHALF + ((tap * 4 + g) * 32 + n) * 8] = v;
        else        *(ull*)&wbfB[(size_t)e * WHALF + ((tap * 4 + g) * 32 + (n - 32)) * 8] = v;
        // fused output zeroing (replaces hipMemsetAsync launch)
        if (bid == 2500 && threadIdx.x == 0) out[0] = 0.f;
    }
}

// ---- T14 split W staging: load early (global->reg), write late (reg->LDS) ----
struct SW { ullx2 a, b, c; };

__device__ __forceinline__ void sw_load(int tid, SW& r, const uchar* wbfB, int e) {
    const uchar* src = wbfB + (size_t)e * WHALF;     // 576 ullx2 chunks
    r.a = *(const ullx2*)(src + tid * 16);
    r.b = *(const ullx2*)(src + (256 + tid) * 16);
    if (tid < 64) r.c = *(const ullx2*)(src + (512 + tid) * 16);
}
__device__ __forceinline__ void sw_write(int tid, uchar* dst, const SW& r) {
    *(ullx2*)(dst + tid * 16) = r.a;
    *(ullx2*)(dst + (256 + tid) * 16) = r.b;
    if (tid < 64) *(ullx2*)(dst + (512 + tid) * 16) = r.c;
}

// ---- one parity class: 3 channel evals sharing the A-tile; single W buffer ----
// Per-eval: barrier (prev readers done) -> write this eval's W (from regs) ->
// issue next eval's W loads -> barrier (W visible) -> compute. All 1344 blocks
// co-resident at 6 blocks/CU, so no makespan tail.
template<int SY0, int SX0, int RSH, int OWSH, int TXH>
__device__ __forceinline__ void class_body(
    int e0, int e_after, SW& sw, float& lpsum,
    int b, int oy0, int ox0, int tid,
    const uchar* Alds, uchar* Wb,
    const uchar* __restrict__ wbfA, const uchar* __restrict__ wbfB,
    const float* __restrict__ value, const float* __restrict__ b1,
    const float* __restrict__ W2, const float* __restrict__ b2)
{
    constexpr int OW = 1 << OWSH;
    const int w = tid >> 6, lane = tid & 63, l15 = lane & 15, l4 = lane >> 4;
    int abase[2];
    #pragma unroll
    for (int a = 0; a < 2; ++a) {
        const int row = w * 32 + a * 16 + l15;
        const int oy = row >> OWSH, ox = row & (OW - 1);
        abase[a] = ((SY0 + 2 * oy) * 2 * TXH + ox) * 24 + l4 * 8;
    }
    const int wfb = l4 * 256 + l15 * 8;

    #pragma unroll 1
    for (int c = 0; c < 3; ++c) {
        const int e = e0 + c;
        const int en = (c < 2) ? (e + 1) : e_after;

        __syncthreads();                 // prev eval's Wb readers done (A visible on 1st)
        sw_write(tid, Wb, sw);           // this eval's W -> LDS
        if (en >= 0) sw_load(tid, sw, wbfB, en);   // prefetch next (spans barrier+compute)
        __syncthreads();                 // Wb visible

        const uchar* wA = wbfA + (size_t)e * WHALF;
        ull breg[9][2];
        #pragma unroll
        for (int tap = 0; tap < 9; ++tap) {
            breg[tap][0] = *(const ull*)(wA + tap * 1024 + wfb);
            breg[tap][1] = *(const ull*)(wA + tap * 1024 + wfb + 128);
        }
        float b1c[4], w2c[4];
        #pragma unroll
        for (int nb = 0; nb < 4; ++nb) {
            b1c[nb] = b1[e * 64 + nb * 16 + l15];
            w2c[nb] = W2[e * 64 + nb * 16 + l15];
        }
        const float bias2 = b2[e];

        floatx4 acc[2][4];
        #pragma unroll
        for (int a = 0; a < 2; ++a)
            #pragma unroll
            for (int nb = 0; nb < 4; ++nb)
                acc[a][nb] = (floatx4){0.f, 0.f, 0.f, 0.f};

        __builtin_amdgcn_s_setprio(1);
        #pragma unroll
        for (int tap = 0; tap < 9; ++tap) {
            const int dy = tap / 3, dx = tap % 3;
            const int v = SX0 + dx + 1;
            const int D = (2 * dy + (v & 1)) * TXH + (v >> 1);   // compile-time px delta
            ull av[2];
            #pragma unroll
            for (int a = 0; a < 2; ++a)
                av[a] = *(const ull*)(Alds + abase[a] + D * 24);
            const ull bv2 = *(const ull*)(Wb + wfb + tap * 1024);
            const ull bv3 = *(const ull*)(Wb + wfb + tap * 1024 + 128);
            #pragma unroll
            for (int a = 0; a < 2; ++a) {
                acc[a][0] = __builtin_amdgcn_mfma_f32_16x16x32_fp8_fp8((long)av[a], (long)breg[tap][0], acc[a][0], 0, 0, 0);
                acc[a][1] = __builtin_amdgcn_mfma_f32_16x16x32_fp8_fp8((long)av[a], (long)breg[tap][1], acc[a][1], 0, 0, 0);
                acc[a][2] = __builtin_amdgcn_mfma_f32_16x16x32_fp8_fp8((long)av[a], (long)bv2, acc[a][2], 0, 0, 0);
                acc[a][3] = __builtin_amdgcn_mfma_f32_16x16x32_fp8_fp8((long)av[a], (long)bv3, acc[a][3], 0, 0, 0);
            }
        }
        __builtin_amdgcn_s_setprio(0);

        // ---- epilogue: 8 row-sums; 32 lanes each finish one row ----
        float zv[8];
        #pragma unroll
        for (int a = 0; a < 2; ++a)
            #pragma unroll
            for (int j = 0; j < 4; ++j) {
                float part = 0.f;
                #pragma unroll
                for (int nb = 0; nb < 4; ++nb)
                    part += w2c[nb] * fmaxf(acc[a][nb][j] + b1c[nb], 0.f);
                zv[a * 4 + j] = row16sum(part);
            }
        if (l15 < 8) {
            const float u0 = (l15 & 1) ? zv[1] : zv[0];
            const float u1 = (l15 & 1) ? zv[3] : zv[2];
            const float u2 = (l15 & 1) ? zv[5] : zv[4];
            const float u3 = (l15 & 1) ? zv[7] : zv[6];
            const float p0 = (l15 & 2) ? u1 : u0;
            const float p1 = (l15 & 2) ? u3 : u2;
            const float zs = ((l15 & 4) ? p1 : p0) + bias2;
            const int row = w * 32 + ((l15 >> 2) << 4) + (l4 << 2) + (l15 & 3);
            const int oyj = oy0 + (row >> OWSH);
            const int oxj = ox0 + (row & (OW - 1));
            const int yj = (SY0 + 2 * oyj) << RSH;
            const int xj = (SX0 + 2 * oxj) << RSH;
            const float xv = value[((size_t)b * 3 + c) * 16384 + yj * 128 + xj];
            const float az = fabsf(zs);
            const float t2 = __builtin_amdgcn_exp2f(-1.442695041f * az);
            const float l1p = 0.69314718056f * __builtin_amdgcn_logf(1.f + t2);
            lpsum += xv * zs + fminf(-zs, 0.f) - l1p;
        }
    }
}

template<int EB, int RSH, int OWSH, int TXH, int TY, int NCLS>
__device__ __forceinline__ void run_level(
    int b, int oy0, int ox0, int tid,
    uchar* Alds, uchar* Wb, float* wsum,
    const uchar* __restrict__ imgbf, const uchar* __restrict__ wbfA,
    const uchar* __restrict__ wbfB, const float* __restrict__ value,
    const float* __restrict__ b1, const float* __restrict__ W2,
    const float* __restrict__ b2, float* __restrict__ out)
{
    constexpr int TPIX = TY * 2 * TXH;
    const int lane = tid & 63, w = tid >> 6;

    // first eval's W half: load early, latency spans the A-stage
    SW sw;
    sw_load(tid, sw, wbfB, EB);

    // ---- stage A-tile (fp8, 24 B/px), shared by all evals of this block ----
    const int yb = 2 * oy0 - 1, xb = 2 * ox0 - 2;
    const uchar* img_b = imgbf + (size_t)b * ((size_t)NB_IMG * 32);
    #pragma unroll
    for (int i = 0; i < (TPIX + 255) / 256; ++i) {
        const int px = tid + i * 256;
        if (px < TPIX) {
            const int typ = px / TXH;
            const int xh = px - typ * TXH;
            const int yl = yb + (typ >> 1);
            const int xl = xb + 2 * xh + (typ & 1);
            int yi = (yl << RSH) + 4; yi = yi < 0 ? 0 : (yi > 135 ? 135 : yi);
            int xi = (xl << RSH) + 4; xi = xi < 0 ? 0 : (xi > 135 ? 135 : xi);
            const uchar* src = img_b + (size_t)(yi * 136 + (xi & 1) * 68 + (xi >> 1)) * 32;
            ullx2 v01 = *(const ullx2*)src;
            ull v2 = *(const ull*)(src + 16);
            uchar* dst = Alds + px * 24;
            *(ull*)dst = v01[0];
            *(ull*)(dst + 8) = v01[1];
            *(ull*)(dst + 16) = v2;
        }
    }
    if (tid < 4) *(ull*)(Alds + TPIX * 24 + tid * 8) = 0ull;   // l4=3 overread guard

    float lpsum = 0.f;
    if constexpr (NCLS == 3) {
        class_body<1, 1, RSH, OWSH, TXH>(EB + 0, EB + 3, sw, lpsum, b, oy0, ox0, tid, Alds, Wb, wbfA, wbfB, value, b1, W2, b2);
        class_body<0, 1, RSH, OWSH, TXH>(EB + 3, EB + 6, sw, lpsum, b, oy0, ox0, tid, Alds, Wb, wbfA, wbfB, value, b1, W2, b2);
        class_body<1, 0, RSH, OWSH, TXH>(EB + 6, -1, sw, lpsum, b, oy0, ox0, tid, Alds, Wb, wbfA, wbfB, value, b1, W2, b2);
    } else {
        class_body<0, 0, RSH, OWSH, TXH>(EB, -1, sw, lpsum, b, oy0, ox0, tid, Alds, Wb, wbfA, wbfB, value, b1, W2, b2);
    }

    lpsum += __shfl_down(lpsum, 32);
    lpsum += __shfl_down(lpsum, 16);
    lpsum += __shfl_down(lpsum, 8);
    lpsum += __shfl_down(lpsum, 4);
    lpsum += __shfl_down(lpsum, 2);
    lpsum += __shfl_down(lpsum, 1);
    if (lane == 0) wsum[w] = lpsum;
    __syncthreads();
    if (tid == 0) atomicAdd(out, wsum[0] + wsum[1] + wsum[2] + wsum[3]);
}

// ---- main kernel: 1344 blocks, ALL co-resident at 6 blocks/CU (LDS 25.6 KB) ----
__global__ __launch_bounds__(256, 6) void pcnn_all(
    const uchar* __restrict__ imgbf, const uchar* __restrict__ wbfA,
    const uchar* __restrict__ wbfB, const float* __restrict__ value,
    const float* __restrict__ b1, const float* __restrict__ W2,
    const float* __restrict__ b2, float* __restrict__ out)
{
    __shared__ __align__(16) uchar Alds[AREG];
    __shared__ __align__(16) uchar Wb[WHALF];
    __shared__ float wsum[4];
    const int bid = blockIdx.x, tid = threadIdx.x;

    // bid = (g*42 + u)*8 + x ; XCD = bid%8 = x ; batch b = g*8+x (all 42 units same XCD)
    const int x = bid & 7, r = bid >> 3;
    const int g = r / 42, u = r - g * 42;
    const int b = g * 8 + x;

    if (u < 32) {                       // fine: e 12..20, r=1; region 4oy x 32ox
        run_level<12, 0, 5, 34, 10, 3>(b, (u >> 1) * 4, (u & 1) * 32, tid, Alds, Wb, wsum,
                                       imgbf, wbfA, wbfB, value, b1, W2, b2, out);
    } else if (u < 40) {                // mid: e 3..11, r=2; region 4oy x 32ox
        run_level<3, 1, 5, 34, 10, 3>(b, (u - 32) * 4, 0, tid, Alds, Wb, wsum,
                                      imgbf, wbfA, wbfB, value, b1, W2, b2, out);
    } else {                            // base: e 0..2, r=4; region 8oy x 16ox
        run_level<0, 2, 4, 17, 18, 1>(b, (u - 40) * 8, 0, tid, Alds, Wb, wsum,
                                      imgbf, wbfA, wbfB, value, b1, W2, b2, out);
    }
}

extern "C" void kernel_launch(void* const* d_in, const int* in_sizes, int n_in,
                              void* d_out, int out_size, void* d_ws, size_t ws_size,
                              hipStream_t stream) {
    const float* value = (const float*)d_in[0];
    const float* dp    = (const float*)d_in[1];
    const float* W1    = (const float*)d_in[2];
    const float* b1    = (const float*)d_in[3];
    const float* W2    = (const float*)d_in[4];
    const float* b2    = (const float*)d_in[5];
    float* out = (float*)d_out;

    uchar* imgbf = (uchar*)d_ws;                                  // 32*18496*32 = 18.94 MB
    uchar* wbfA  = imgbf + (size_t)32 * NB_IMG * 32;              // 21*9216 B
    uchar* wbfB  = wbfA + (size_t)21 * WHALF;                     // 21*9216 B

    hipLaunchKernelGGL(prep_kernel, dim3(2501), dim3(256), 0, stream,
                       value, dp, W1, imgbf, wbfA, wbfB, out);
    hipLaunchKernelGGL(pcnn_all, dim3(1344), dim3(256), 0, stream,
                       imgbf, wbfA, wbfB, value, b1, W2, b2, out);
}

// Round 15
// 78.441 us; speedup vs baseline: 2.1677x; 2.1677x over previous
//
#include <hip/hip_runtime.h>

typedef unsigned char uchar;
typedef unsigned long long ull;
typedef __attribute__((ext_vector_type(2))) unsigned long long ullx2;
typedef __attribute__((ext_vector_type(4))) float floatx4;
typedef __attribute__((ext_vector_type(4))) unsigned int uintx4;

#define NB_IMG 18496      // 136 y * 2 p * 68 xh pixel slots per batch image
#define WHALF 9216        // bytes per eval per weight half (9*4*32*8)
#define AREG 16352        // A-tile LDS bytes (max 680 px * 24 B + 32 guard)

// ---- fp32 -> fp8 e4m3 (OCP), RNE ----
__device__ __forceinline__ uchar f2e4(float x) {
    float a = fabsf(x);
    unsigned s = (__float_as_uint(x) >> 24) & 0x80u;
    if (a >= 448.f) return (uchar)(s | 0x7E);
    if (a < 0.015625f) {
        int m = (int)rintf(a * 512.f);
        return (uchar)(s | (unsigned)m);
    }
    unsigned u = __float_as_uint(a);
    unsigned r = u + 0x7FFFFu + ((u >> 20) & 1u);
    unsigned e8 = (r >> 23) - 120u;
    return (uchar)(s | (e8 << 3) | ((r >> 20) & 7u));
}

// 16-lane DPP row sum (all lanes get row total)
__device__ __forceinline__ float row16sum(float v) {
    v += __int_as_float(__builtin_amdgcn_update_dpp(0, __float_as_int(v), 0x128, 0xf, 0xf, false));
    v += __int_as_float(__builtin_amdgcn_update_dpp(0, __float_as_int(v), 0x124, 0xf, 0xf, false));
    v += __int_as_float(__builtin_amdgcn_update_dpp(0, __float_as_int(v), 0x122, 0xf, 0xf, false));
    v += __int_as_float(__builtin_amdgcn_update_dpp(0, __float_as_int(v), 0x121, 0xf, 0xf, false));
    return v;
}

__device__ __forceinline__ void eval_geom(int e, int& sy0, int& sx0, int& cch, int& s_idx) {
    if (e < 3) { sy0 = 0; sx0 = 0; cch = e; s_idx = -1; }
    else {
        int u = e - 3; int s = (u % 9) / 3; cch = u % 3; s_idx = s;
        sy0 = (s == 1) ? 0 : 1;
        sx0 = (s == 2) ? 0 : 1;
    }
}

__device__ __forceinline__ bool tap_active(int e, int ci, int dy, int dx,
                                           int sy0, int sx0, int cch, int s_idx) {
    if (ci >= 3) return true;
    int py = (sy0 + dy - 1) & 1;
    int px = (sx0 + dx - 1) & 1;
    if (e < 3) return (py == 0 && px == 0) && (ci < cch);
    if (py == 0 && px == 0) return true;
    int sp = (py == 1 && px == 1) ? 0 : ((py == 0 && px == 1) ? 1 : 2);
    return (sp < s_idx) || (sp == s_idx && ci < cch);
}

// ---- merged prepass: cvt (blocks 0..2311) + weight pack (blocks 2312..2500) ----
__global__ __launch_bounds__(256) void prep_kernel(
    const float* __restrict__ value, const float* __restrict__ dp,
    const float* __restrict__ W1,
    uchar* __restrict__ imgbf, uchar* __restrict__ wbfA, uchar* __restrict__ wbfB,
    float* __restrict__ out)
{
    const int bid = blockIdx.x;
    if (bid < 2312) {
        const int t = bid * 256 + threadIdx.x;   // 591872 slots exactly
        const int b = t / NB_IMG;
        const int r = t - b * NB_IMG;
        const int y = r / 136;
        const int rr = r - y * 136;
        const int p = rr / 68;
        const int xh = rr - p * 68;
        const int yi = y - 4;
        const int xi = 2 * (xh - 2) + p;
        unsigned d[8];
        #pragma unroll
        for (int i = 0; i < 8; ++i) d[i] = 0;
        if ((unsigned)yi < 128u && (unsigned)xi < 128u) {
            const int o = yi * 128 + xi;
            const float* vb = value + (size_t)b * 3 * 16384 + o;
            const float* pb = dp + (size_t)b * 16 * 16384 + o;
            #pragma unroll
            for (int i = 0; i < 3; ++i) d[i >> 2] |= (unsigned)f2e4(vb[i * 16384]) << ((i & 3) * 8);
            #pragma unroll
            for (int i = 0; i < 16; ++i) {
                const int ci = 3 + i;
                d[ci >> 2] |= (unsigned)f2e4(pb[i * 16384]) << ((ci & 3) * 8);
            }
        }
        uchar* dst = imgbf + (size_t)t * 32;
        uintx4 v0, v1;
        v0[0] = d[0]; v0[1] = d[1]; v0[2] = d[2]; v0[3] = d[3];
        v1[0] = d[4]; v1[1] = d[5]; v1[2] = d[6]; v1[3] = d[7];
        *(uintx4*)dst = v0;
        *(uintx4*)(dst + 16) = v1;
    } else {
        // masked fp8 weights, fragment-major; cols 0..31 -> wbfA, 32..63 -> wbfB
        const int q = bid - 2312;                // 0..188
        const int e = q / 9, tap = q % 9;
        const int g = threadIdx.x >> 6, n = threadIdx.x & 63;
        int sy0, sx0, cch, s_idx;
        eval_geom(e, sy0, sx0, cch, s_idx);
        const int dy = tap / 3, dx = tap % 3;
        const float* wrow = W1 + ((size_t)e * 64 + n) * 171;
        ull v = 0;
        #pragma unroll
        for (int qq = 0; qq < 8; ++qq) {
            const int ci = g * 8 + qq;
            float w = 0.f;
            if (ci < 19 && tap_active(e, ci, dy, dx, sy0, sx0, cch, s_idx))
                w = wrow[ci * 9 + tap];
            v |= (ull)f2e4(w) << (qq * 8);
        }
        if (n < 32) *(ull*)&wbfA[(size_t)e * WHALF + ((tap * 4 + g) * 32 + n) * 8] = v;
        else        *(ull*)&wbfB[(size_t)e * WHALF + ((tap * 4 + g) * 32 + (n - 32)) * 8] = v;
        // fused output zeroing (replaces hipMemsetAsync launch)
        if (bid == 2500 && threadIdx.x == 0) out[0] = 0.f;
    }
}

// ---- T14 split W staging: load early (global->reg), write late (reg->LDS) ----
struct SW { ullx2 a, b, c; };

__device__ __forceinline__ void sw_load(int tid, SW& r, const uchar* wbfB, int e) {
    const uchar* src = wbfB + (size_t)e * WHALF;     // 576 ullx2 chunks
    r.a = *(const ullx2*)(src + tid * 16);
    r.b = *(const ullx2*)(src + (256 + tid) * 16);
    if (tid < 64) r.c = *(const ullx2*)(src + (512 + tid) * 16);
}
__device__ __forceinline__ void sw_write(int tid, uchar* dst, const SW& r) {
    *(ullx2*)(dst + tid * 16) = r.a;
    *(ullx2*)(dst + (256 + tid) * 16) = r.b;
    if (tid < 64) *(ullx2*)(dst + (512 + tid) * 16) = r.c;
}

// ---- one parity class: 3 channel evals sharing the A-tile; single W buffer ----
template<int SY0, int SX0, int RSH, int OWSH, int TXH>
__device__ __forceinline__ void class_body(
    int e0, int e_after, SW& sw, float& lpsum,
    int b, int oy0, int ox0, int tid,
    const uchar* Alds, uchar* Wb,
    const uchar* __restrict__ wbfA, const uchar* __restrict__ wbfB,
    const float* __restrict__ value, const float* __restrict__ b1,
    const float* __restrict__ W2, const float* __restrict__ b2)
{
    constexpr int OW = 1 << OWSH;
    const int w = tid >> 6, lane = tid & 63, l15 = lane & 15, l4 = lane >> 4;
    int abase[2];
    #pragma unroll
    for (int a = 0; a < 2; ++a) {
        const int row = w * 32 + a * 16 + l15;
        const int oy = row >> OWSH, ox = row & (OW - 1);
        abase[a] = ((SY0 + 2 * oy) * 2 * TXH + ox) * 24 + l4 * 8;
    }
    const int wfb = l4 * 256 + l15 * 8;

    #pragma unroll 1
    for (int c = 0; c < 3; ++c) {
        const int e = e0 + c;
        const int en = (c < 2) ? (e + 1) : e_after;

        __syncthreads();                 // prev eval's Wb readers done (A visible on 1st)
        sw_write(tid, Wb, sw);           // this eval's W -> LDS
        if (en >= 0) sw_load(tid, sw, wbfB, en);   // prefetch next (spans barrier+compute)
        __syncthreads();                 // Wb visible

        const uchar* wA = wbfA + (size_t)e * WHALF;
        ull breg[9][2];
        #pragma unroll
        for (int tap = 0; tap < 9; ++tap) {
            breg[tap][0] = *(const ull*)(wA + tap * 1024 + wfb);
            breg[tap][1] = *(const ull*)(wA + tap * 1024 + wfb + 128);
        }
        float b1c[4], w2c[4];
        #pragma unroll
        for (int nb = 0; nb < 4; ++nb) {
            b1c[nb] = b1[e * 64 + nb * 16 + l15];
            w2c[nb] = W2[e * 64 + nb * 16 + l15];
        }
        const float bias2 = b2[e];

        floatx4 acc[2][4];
        #pragma unroll
        for (int a = 0; a < 2; ++a)
            #pragma unroll
            for (int nb = 0; nb < 4; ++nb)
                acc[a][nb] = (floatx4){0.f, 0.f, 0.f, 0.f};

        __builtin_amdgcn_s_setprio(1);
        #pragma unroll
        for (int tap = 0; tap < 9; ++tap) {
            const int dy = tap / 3, dx = tap % 3;
            const int v = SX0 + dx + 1;
            const int D = (2 * dy + (v & 1)) * TXH + (v >> 1);   // compile-time px delta
            ull av[2];
            #pragma unroll
            for (int a = 0; a < 2; ++a)
                av[a] = *(const ull*)(Alds + abase[a] + D * 24);
            const ull bv2 = *(const ull*)(Wb + wfb + tap * 1024);
            const ull bv3 = *(const ull*)(Wb + wfb + tap * 1024 + 128);
            #pragma unroll
            for (int a = 0; a < 2; ++a) {
                acc[a][0] = __builtin_amdgcn_mfma_f32_16x16x32_fp8_fp8((long)av[a], (long)breg[tap][0], acc[a][0], 0, 0, 0);
                acc[a][1] = __builtin_amdgcn_mfma_f32_16x16x32_fp8_fp8((long)av[a], (long)breg[tap][1], acc[a][1], 0, 0, 0);
                acc[a][2] = __builtin_amdgcn_mfma_f32_16x16x32_fp8_fp8((long)av[a], (long)bv2, acc[a][2], 0, 0, 0);
                acc[a][3] = __builtin_amdgcn_mfma_f32_16x16x32_fp8_fp8((long)av[a], (long)bv3, acc[a][3], 0, 0, 0);
            }
        }
        __builtin_amdgcn_s_setprio(0);

        // ---- epilogue: 8 row-sums; 32 lanes each finish one row ----
        float zv[8];
        #pragma unroll
        for (int a = 0; a < 2; ++a)
            #pragma unroll
            for (int j = 0; j < 4; ++j) {
                float part = 0.f;
                #pragma unroll
                for (int nb = 0; nb < 4; ++nb)
                    part += w2c[nb] * fmaxf(acc[a][nb][j] + b1c[nb], 0.f);
                zv[a * 4 + j] = row16sum(part);
            }
        if (l15 < 8) {
            const float u0 = (l15 & 1) ? zv[1] : zv[0];
            const float u1 = (l15 & 1) ? zv[3] : zv[2];
            const float u2 = (l15 & 1) ? zv[5] : zv[4];
            const float u3 = (l15 & 1) ? zv[7] : zv[6];
            const float p0 = (l15 & 2) ? u1 : u0;
            const float p1 = (l15 & 2) ? u3 : u2;
            const float zs = ((l15 & 4) ? p1 : p0) + bias2;
            const int row = w * 32 + ((l15 >> 2) << 4) + (l4 << 2) + (l15 & 3);
            const int oyj = oy0 + (row >> OWSH);
            const int oxj = ox0 + (row & (OW - 1));
            const int yj = (SY0 + 2 * oyj) << RSH;
            const int xj = (SX0 + 2 * oxj) << RSH;
            const float xv = value[((size_t)b * 3 + c) * 16384 + yj * 128 + xj];
            const float az = fabsf(zs);
            const float t2 = __builtin_amdgcn_exp2f(-1.442695041f * az);
            const float l1p = 0.69314718056f * __builtin_amdgcn_logf(1.f + t2);
            lpsum += xv * zs + fminf(-zs, 0.f) - l1p;
        }
    }
}

template<int EB, int RSH, int OWSH, int TXH, int TY, int NCLS>
__device__ __forceinline__ void run_level(
    int b, int oy0, int ox0, int tid,
    uchar* Alds, uchar* Wb, float* wsum,
    const uchar* __restrict__ imgbf, const uchar* __restrict__ wbfA,
    const uchar* __restrict__ wbfB, const float* __restrict__ value,
    const float* __restrict__ b1, const float* __restrict__ W2,
    const float* __restrict__ b2, float* __restrict__ out)
{
    constexpr int TPIX = TY * 2 * TXH;
    const int lane = tid & 63, w = tid >> 6;

    // first eval's W half: load early, latency spans the A-stage
    SW sw;
    sw_load(tid, sw, wbfB, EB);

    // ---- stage A-tile (fp8, 24 B/px), shared by all evals of this block ----
    const int yb = 2 * oy0 - 1, xb = 2 * ox0 - 2;
    const uchar* img_b = imgbf + (size_t)b * ((size_t)NB_IMG * 32);
    #pragma unroll
    for (int i = 0; i < (TPIX + 255) / 256; ++i) {
        const int px = tid + i * 256;
        if (px < TPIX) {
            const int typ = px / TXH;
            const int xh = px - typ * TXH;
            const int yl = yb + (typ >> 1);
            const int xl = xb + 2 * xh + (typ & 1);
            int yi = (yl << RSH) + 4; yi = yi < 0 ? 0 : (yi > 135 ? 135 : yi);
            int xi = (xl << RSH) + 4; xi = xi < 0 ? 0 : (xi > 135 ? 135 : xi);
            const uchar* src = img_b + (size_t)(yi * 136 + (xi & 1) * 68 + (xi >> 1)) * 32;
            ullx2 v01 = *(const ullx2*)src;
            ull v2 = *(const ull*)(src + 16);
            uchar* dst = Alds + px * 24;
            *(ull*)dst = v01[0];
            *(ull*)(dst + 8) = v01[1];
            *(ull*)(dst + 16) = v2;
        }
    }
    if (tid < 4) *(ull*)(Alds + TPIX * 24 + tid * 8) = 0ull;   // l4=3 overread guard

    float lpsum = 0.f;
    if constexpr (NCLS == 3) {
        class_body<1, 1, RSH, OWSH, TXH>(EB + 0, EB + 3, sw, lpsum, b, oy0, ox0, tid, Alds, Wb, wbfA, wbfB, value, b1, W2, b2);
        class_body<0, 1, RSH, OWSH, TXH>(EB + 3, EB + 6, sw, lpsum, b, oy0, ox0, tid, Alds, Wb, wbfA, wbfB, value, b1, W2, b2);
        class_body<1, 0, RSH, OWSH, TXH>(EB + 6, -1, sw, lpsum, b, oy0, ox0, tid, Alds, Wb, wbfA, wbfB, value, b1, W2, b2);
    } else {
        class_body<0, 0, RSH, OWSH, TXH>(EB, -1, sw, lpsum, b, oy0, ox0, tid, Alds, Wb, wbfA, wbfB, value, b1, W2, b2);
    }

    lpsum += __shfl_down(lpsum, 32);
    lpsum += __shfl_down(lpsum, 16);
    lpsum += __shfl_down(lpsum, 8);
    lpsum += __shfl_down(lpsum, 4);
    lpsum += __shfl_down(lpsum, 2);
    lpsum += __shfl_down(lpsum, 1);
    if (lane == 0) wsum[w] = lpsum;
    __syncthreads();
    if (tid == 0) atomicAdd(out, wsum[0] + wsum[1] + wsum[2] + wsum[3]);
}

// ---- main kernel: 1344 blocks; LDS 25.6 KB -> HW can co-schedule 6 blocks/CU.
// launch_bounds stays (256,4): r14 showed (256,6) strangles the allocator to
// 40 VGPR and spills ~530 MB to scratch. VGPR=64 naturally supports 8 waves/SIMD;
// residency is then LDS-limited at 6 blocks/CU without any allocator pressure.
__global__ __launch_bounds__(256, 4) void pcnn_all(
    const uchar* __restrict__ imgbf, const uchar* __restrict__ wbfA,
    const uchar* __restrict__ wbfB, const float* __restrict__ value,
    const float* __restrict__ b1, const float* __restrict__ W2,
    const float* __restrict__ b2, float* __restrict__ out)
{
    __shared__ __align__(16) uchar Alds[AREG];
    __shared__ __align__(16) uchar Wb[WHALF];
    __shared__ float wsum[4];
    const int bid = blockIdx.x, tid = threadIdx.x;

    // bid = (g*42 + u)*8 + x ; XCD = bid%8 = x ; batch b = g*8+x (all 42 units same XCD)
    const int x = bid & 7, r = bid >> 3;
    const int g = r / 42, u = r - g * 42;
    const int b = g * 8 + x;

    if (u < 32) {                       // fine: e 12..20, r=1; region 4oy x 32ox
        run_level<12, 0, 5, 34, 10, 3>(b, (u >> 1) * 4, (u & 1) * 32, tid, Alds, Wb, wsum,
                                       imgbf, wbfA, wbfB, value, b1, W2, b2, out);
    } else if (u < 40) {                // mid: e 3..11, r=2; region 4oy x 32ox
        run_level<3, 1, 5, 34, 10, 3>(b, (u - 32) * 4, 0, tid, Alds, Wb, wsum,
                                      imgbf, wbfA, wbfB, value, b1, W2, b2, out);
    } else {                            // base: e 0..2, r=4; region 8oy x 16ox
        run_level<0, 2, 4, 17, 18, 1>(b, (u - 40) * 8, 0, tid, Alds, Wb, wsum,
                                      imgbf, wbfA, wbfB, value, b1, W2, b2, out);
    }
}

extern "C" void kernel_launch(void* const* d_in, const int* in_sizes, int n_in,
                              void* d_out, int out_size, void* d_ws, size_t ws_size,
                              hipStream_t stream) {
    const float* value = (const float*)d_in[0];
    const float* dp    = (const float*)d_in[1];
    const float* W1    = (const float*)d_in[2];
    const float* b1    = (const float*)d_in[3];
    const float* W2    = (const float*)d_in[4];
    const float* b2    = (const float*)d_in[5];
    float* out = (float*)d_out;

    uchar* imgbf = (uchar*)d_ws;                                  // 32*18496*32 = 18.94 MB
    uchar* wbfA  = imgbf + (size_t)32 * NB_IMG * 32;              // 21*9216 B
    uchar* wbfB  = wbfA + (size_t)21 * WHALF;                     // 21*9216 B

    hipLaunchKernelGGL(prep_kernel, dim3(2501), dim3(256), 0, stream,
                       value, dp, W1, imgbf, wbfA, wbfB, out);
    hipLaunchKernelGGL(pcnn_all, dim3(1344), dim3(256), 0, stream,
                       imgbf, wbfA, wbfB, value, b1, W2, b2, out);
}